// Round 12
// baseline (939.593 us; speedup 1.0000x reference)
//
#include <hip/hip_runtime.h>
#include <cmath>

typedef __attribute__((ext_vector_type(8))) short short8;
typedef __attribute__((ext_vector_type(4))) float floatx4;

// ---------- helpers ----------
__device__ __forceinline__ unsigned short rnbf(float f) {
    unsigned u = __float_as_uint(f);
    u += 0x7fffu + ((u >> 16) & 1u);
    return (unsigned short)(u >> 16);
}
__device__ __forceinline__ float bf2f(unsigned short h) {
    return __uint_as_float(((unsigned)h) << 16);
}
__device__ __forceinline__ int rfl(int v) { return __builtin_amdgcn_readfirstlane(v); }

// ---------- K0: encoder. one wave per node ----------
__global__ __launch_bounds__(64) void k_encoder(
    const float* __restrict__ x,
    const float* __restrict__ Wn, const float* __restrict__ bn,
    const float* __restrict__ Wroot1, const float* __restrict__ b1,
    float* __restrict__ nbuf, float* __restrict__ acc1)
{
    int i = blockIdx.x;
    int j = threadIdx.x;
    __shared__ __align__(16) float nS[64];
    float x0 = x[3*i], x1 = x[3*i+1], x2 = x[3*i+2];
    float nj = fmaxf(fmaf(x2, Wn[128+j], fmaf(x1, Wn[64+j], fmaf(x0, Wn[j], bn[j]))), 0.f);
    size_t o64 = (size_t)i*64 + j;
    nbuf[o64] = nj;
    nS[j] = nj;
    __syncthreads();
    float acc = b1[j];
    const float4* n4 = (const float4*)nS;
    #pragma unroll
    for (int c = 0; c < 16; ++c) {
        float4 f = n4[c];
        acc = fmaf(f.x, Wroot1[(4*c+0)*64+j], acc);
        acc = fmaf(f.y, Wroot1[(4*c+1)*64+j], acc);
        acc = fmaf(f.z, Wroot1[(4*c+2)*64+j], acc);
        acc = fmaf(f.w, Wroot1[(4*c+3)*64+j], acc);
    }
    acc1[o64] = acc;
}

// ---------- (dst,rel)-key histogram ----------
__global__ void k_histd(const int* __restrict__ ei, const int* __restrict__ et,
                        int* __restrict__ deg8, int E)
{
    int e = blockIdx.x*blockDim.x + threadIdx.x;
    if (e < E) atomicAdd(&deg8[ei[E + e]*8 + et[e]], 1);
}

// ---------- counting-sort scan over K=N*8 keys ----------
#define SCHUNK 1024
__global__ void k_bsum(const int* __restrict__ deg, int* __restrict__ bsum, int K)
{
    __shared__ int s[256];
    int b = blockIdx.x, t = threadIdx.x;
    int base = b*SCHUNK;
    int v = 0;
    for (int k = t; k < SCHUNK; k += 256) { int i = base + k; v += (i < K) ? deg[i] : 0; }
    s[t] = v; __syncthreads();
    for (int o = 128; o; o >>= 1) { if (t < o) s[t] += s[t+o]; __syncthreads(); }
    if (t == 0) bsum[b] = s[0];
}
__global__ void k_bscan(int* __restrict__ bsum, int nb)
{
    __shared__ int ts[256];
    int t = threadIdx.x;
    int v[4]; int loc = 0;
    #pragma unroll
    for (int u = 0; u < 4; ++u) { int i = t*4+u; v[u] = (i < nb) ? bsum[i] : 0; loc += v[u]; }
    ts[t] = loc; __syncthreads();
    for (int o = 1; o < 256; o <<= 1) {
        int add = (t >= o) ? ts[t-o] : 0;
        __syncthreads();
        ts[t] += add;
        __syncthreads();
    }
    int excl = ts[t] - loc;
    #pragma unroll
    for (int u = 0; u < 4; ++u) {
        int i = t*4+u;
        if (i < nb) bsum[i] = excl;
        excl += v[u];
    }
}
__global__ void k_bapply(const int* __restrict__ deg, const int* __restrict__ bsum,
                         int* __restrict__ off, int* __restrict__ cursor, int K)
{
    __shared__ int ts[256];
    int b = blockIdx.x, t = threadIdx.x;
    int base = b*SCHUNK;
    int v[4]; int loc = 0;
    #pragma unroll
    for (int u = 0; u < 4; ++u) { int i = base + t*4 + u; v[u] = (i < K) ? deg[i] : 0; loc += v[u]; }
    ts[t] = loc; __syncthreads();
    for (int o = 1; o < 256; o <<= 1) {
        int add = (t >= o) ? ts[t-o] : 0;
        __syncthreads();
        ts[t] += add;
        __syncthreads();
    }
    int excl = ts[t] - loc + bsum[b];
    #pragma unroll
    for (int u = 0; u < 4; ++u) {
        int i = base + t*4 + u;
        if (i < K) { off[i] = excl; cursor[i] = excl; }
        excl += v[u];
        if (i == K-1) off[K] = excl;
    }
}

// ---------- scatter edges into (dst,rel)-sorted order, packed int2 ----------
// x = src | rel<<24 ; y = bf16(a0)<<16 | bf16(a1)
__global__ void k_scatd(const int* __restrict__ ei, const float* __restrict__ ea,
                        const int* __restrict__ et, int* __restrict__ cursor,
                        int2* __restrict__ srec, int E)
{
    int e = blockIdx.x*blockDim.x + threadIdx.x;
    if (e >= E) return;
    int rel = et[e];
    int key = ei[E + e]*8 + rel;
    int pos = atomicAdd(&cursor[key], 1);
    float2 a = ((const float2*)ea)[e];
    int xv = ei[e] | (rel << 24);
    int yv = ((int)rnbf(a.x) << 16) | (int)rnbf(a.y);
    srec[pos] = make_int2(xv, yv);
}

// ---------- pack W1A/W2 into MFMA B-fragment order, split bf16 hi/lo ----------
// units: [0,16)=W1A rel=u>>1,ks=u&1 rows0..63 of W1; [16,32)=W2 same
__global__ __launch_bounds__(64) void k_wpack(
    const float* __restrict__ W1, const float* __restrict__ W2,
    unsigned short* __restrict__ wpk)
{
    int unit = blockIdx.x >> 2;
    int jt = blockIdx.x & 3;
    int lane = threadIdx.x;
    const float* Wb;
    int kbase;
    if (unit < 16) {
        Wb = W1 + (size_t)(unit >> 1)*96*64;
        kbase = (unit & 1)*32;
    } else {
        Wb = W2 + (size_t)((unit - 16) >> 1)*64*64;
        kbase = ((unit - 16) & 1)*32;
    }
    int j = jt*16 + (lane & 15);
    size_t base = (((size_t)unit*4 + jt)*64 + lane)*16;
    #pragma unroll
    for (int i = 0; i < 8; ++i) {
        int k = kbase + (lane >> 4)*8 + i;
        float f = Wb[(size_t)k*64 + j];
        unsigned short hi = rnbf(f);
        unsigned short lo = rnbf(f - bf2f(hi));
        wpk[base + i] = hi;
        wpk[base + 8 + i] = lo;
    }
}

// ---------- dense GEMM via MFMA split-bf16, bf16 output ----------
__global__ __launch_bounds__(256) void k_vgemmB(
    const float* __restrict__ F, const unsigned short* __restrict__ wpk,
    int unitBase, int g0, int Gc, unsigned short* __restrict__ Vbf,
    size_t plane, int N)
{
    int lane = threadIdx.x & 63;
    int wave = threadIdx.x >> 6;
    int n0 = blockIdx.x*64 + 16*wave;
    int m = lane & 15, q = lane >> 4;
    int node = n0 + m;
    if (node >= N) node = N - 1;
    const float4* Fr = (const float4*)(F + (size_t)node*64);
    short8 ah[2], al[2];
    #pragma unroll
    for (int ks = 0; ks < 2; ++ks) {
        float4 u0 = Fr[ks*8 + q*2];
        float4 u1 = Fr[ks*8 + q*2 + 1];
        float fv[8] = {u0.x,u0.y,u0.z,u0.w,u1.x,u1.y,u1.z,u1.w};
        #pragma unroll
        for (int i = 0; i < 8; ++i) {
            unsigned short hb = rnbf(fv[i]);
            ah[ks][i] = (short)hb;
            al[ks][i] = (short)rnbf(fv[i] - bf2f(hb));
        }
    }
    for (int p = 0; p < Gc; ++p) {
        int rel = g0 + p;
        floatx4 acc[4];
        #pragma unroll
        for (int jt = 0; jt < 4; ++jt) acc[jt] = (floatx4){0.f,0.f,0.f,0.f};
        #pragma unroll
        for (int ks = 0; ks < 2; ++ks) {
            int unit = unitBase + rel*2 + ks;
            #pragma unroll
            for (int jt = 0; jt < 4; ++jt) {
                const unsigned short* qp = wpk + (((size_t)unit*4 + jt)*64 + lane)*16;
                short8 bh = *(const short8*)qp;
                short8 bl = *(const short8*)(qp + 8);
                acc[jt] = __builtin_amdgcn_mfma_f32_16x16x32_bf16(ah[ks], bh, acc[jt], 0,0,0);
                acc[jt] = __builtin_amdgcn_mfma_f32_16x16x32_bf16(ah[ks], bl, acc[jt], 0,0,0);
                acc[jt] = __builtin_amdgcn_mfma_f32_16x16x32_bf16(al[ks], bh, acc[jt], 0,0,0);
            }
        }
        unsigned short* Vp = Vbf + (size_t)p*plane;
        #pragma unroll
        for (int jt = 0; jt < 4; ++jt) {
            #pragma unroll
            for (int t = 0; t < 4; ++t) {
                int row = n0 + q*4 + t;
                if (row < N) Vp[(size_t)row*64 + jt*16 + m] = rnbf(acc[jt][t]);
            }
        }
    }
}

// ---------- layer-1 pass 1: run-wise, uniform broadcast loads, no shfl/branches.
// V-gather rels [0,Gc) + e-path all rels (register se[8]) + end flush GEMVs.
__global__ __launch_bounds__(256) void k_agg1e(
    const int2* __restrict__ srec, const int* __restrict__ off8,
    const unsigned short* __restrict__ Vbf, size_t plane,
    const float* __restrict__ W1, const float* __restrict__ We,
    const float* __restrict__ be,
    float* __restrict__ acc1, int N, int Gc)
{
    __shared__ unsigned short WB[8*32*64];   // 32 KB bf16 W1B (rows 64..95 of W1)
    __shared__ float seS[4][32];
    int lane = threadIdx.x & 63;
    int wv = threadIdx.x >> 6;
    for (int idx = threadIdx.x; idx < 16384; idx += 256) {
        int rel = idx >> 11, rem = idx & 2047;
        WB[idx] = rnbf(W1[(size_t)rel*6144 + 4096 + rem]);
    }
    __syncthreads();
    float we0 = We[lane & 31], we1 = We[32 + (lane & 31)], bev = be[lane & 31];
    int stride = gridDim.x*4;
    for (int node = blockIdx.x*4 + wv; node < N; node += stride) {
        int o[9];
        #pragma unroll
        for (int r = 0; r < 9; ++r) o[r] = rfl(off8[node*8 + r]);
        if (o[0] == o[8]) continue;                    // isolated node
        float vsum = 0.f;
        // ---- V-gather, unrolled runs (break past Gc) ----
        #pragma unroll
        for (int r = 0; r < 8; ++r) {
            if (r >= Gc) break;                        // wave-uniform
            int s = o[r], e = o[r+1];
            const unsigned short* Vp = Vbf + (size_t)r*plane;
            int i = s;
            for (; i + 4 <= e; i += 4) {
                int sx[4];
                #pragma unroll
                for (int u = 0; u < 4; ++u) sx[u] = rfl(srec[i+u].x) & 0xFFFFFF;
                float vg[4];
                #pragma unroll
                for (int u = 0; u < 4; ++u) vg[u] = bf2f(Vp[(size_t)sx[u]*64 + lane]);
                vsum += (vg[0]+vg[1]) + (vg[2]+vg[3]);
            }
            for (; i < e; ++i) {
                int sx = rfl(srec[i].x) & 0xFFFFFF;
                vsum += bf2f(Vp[(size_t)sx*64 + lane]);
            }
        }
        // ---- e-path, all rels, register accumulators ----
        float se[8];
        #pragma unroll
        for (int r = 0; r < 8; ++r) se[r] = 0.f;
        #pragma unroll
        for (int r = 0; r < 8; ++r) {
            int s = o[r], e = o[r+1];
            float ev = 0.f;
            int i = s;
            for (; i + 4 <= e; i += 4) {
                int ry[4];
                #pragma unroll
                for (int u = 0; u < 4; ++u) ry[u] = rfl(srec[i+u].y);
                #pragma unroll
                for (int u = 0; u < 4; ++u) {
                    float a0 = __uint_as_float((unsigned)ry[u] & 0xFFFF0000u);
                    float a1 = __uint_as_float(((unsigned)ry[u]) << 16);
                    ev += fmaxf(fmaf(a1, we1, fmaf(a0, we0, bev)), 0.f);
                }
            }
            for (; i < e; ++i) {
                int ry = rfl(srec[i].y);
                float a0 = __uint_as_float((unsigned)ry & 0xFFFF0000u);
                float a1 = __uint_as_float(((unsigned)ry) << 16);
                ev += fmaxf(fmaf(a1, we1, fmaf(a0, we0, bev)), 0.f);
            }
            se[r] = ev;
        }
        // ---- flush: vsum += sum_r se[r] @ W1B[r] (skip empty runs) ----
        #pragma unroll
        for (int r = 0; r < 8; ++r) {
            if (o[r] == o[r+1]) continue;              // wave-uniform
            if (lane < 32) seS[wv][lane] = se[r];
            float aa = 0.f, ab = 0.f;
            #pragma unroll
            for (int mm = 0; mm < 16; ++mm) {
                aa = fmaf(seS[wv][mm],    bf2f(WB[r*2048 + mm*64 + lane]), aa);
                ab = fmaf(seS[wv][16+mm], bf2f(WB[r*2048 + (16+mm)*64 + lane]), ab);
            }
            vsum += aa + ab;
        }
        acc1[(size_t)node*64 + lane] += vsum;
    }
}

// ---------- layer-1 pass 2+: run-wise V-gather only, rels [g0,g1) ----------
__global__ __launch_bounds__(256) void k_agg1v(
    const int2* __restrict__ srec, const int* __restrict__ off8,
    const unsigned short* __restrict__ Vbf, size_t plane,
    float* __restrict__ acc1, int N, int g0, int g1)
{
    int lane = threadIdx.x & 63;
    int wv = threadIdx.x >> 6;
    int stride = gridDim.x*4;
    for (int node = blockIdx.x*4 + wv; node < N; node += stride) {
        float vsum = 0.f;
        bool any = false;
        for (int r = g0; r < g1; ++r) {
            int s = rfl(off8[node*8 + r]);
            int e = rfl(off8[node*8 + r + 1]);
            if (s == e) continue;
            any = true;
            const unsigned short* Vp = Vbf + (size_t)(r - g0)*plane;
            int i = s;
            for (; i + 4 <= e; i += 4) {
                int sx[4];
                #pragma unroll
                for (int u = 0; u < 4; ++u) sx[u] = rfl(srec[i+u].x) & 0xFFFFFF;
                float vg[4];
                #pragma unroll
                for (int u = 0; u < 4; ++u) vg[u] = bf2f(Vp[(size_t)sx[u]*64 + lane]);
                vsum += (vg[0]+vg[1]) + (vg[2]+vg[3]);
            }
            for (; i < e; ++i) {
                int sx = rfl(srec[i].x) & 0xFFFFFF;
                vsum += bf2f(Vp[(size_t)sx*64 + lane]);
            }
        }
        if (any) acc1[(size_t)node*64 + lane] += vsum;
    }
}

// ---------- fused relu + root2: acc1->h in place; acc2 = h@Wroot2+b2 ----------
__global__ __launch_bounds__(64) void k_hrow(
    float* __restrict__ acc1, float* __restrict__ acc2,
    const float* __restrict__ Wroot2, const float* __restrict__ b2)
{
    int i = blockIdx.x, j = threadIdx.x;
    __shared__ __align__(16) float hS[64];
    size_t o64 = (size_t)i*64 + j;
    float h = fmaxf(acc1[o64], 0.f);
    acc1[o64] = h;
    hS[j] = h;
    __syncthreads();
    float acc = b2[j];
    const float4* h4 = (const float4*)hS;
    #pragma unroll
    for (int c = 0; c < 16; ++c) {
        float4 f = h4[c];
        acc = fmaf(f.x, Wroot2[(4*c+0)*64+j], acc);
        acc = fmaf(f.y, Wroot2[(4*c+1)*64+j], acc);
        acc = fmaf(f.z, Wroot2[(4*c+2)*64+j], acc);
        acc = fmaf(f.w, Wroot2[(4*c+3)*64+j], acc);
    }
    acc2[o64] = acc;
}

// ---------- layer-2: run-wise max per (node,rel), rels [g0,g1) ----------
__global__ __launch_bounds__(256) void k_agg2(
    const int2* __restrict__ srec, const int* __restrict__ off8,
    const unsigned short* __restrict__ Ubf, size_t plane,
    float* __restrict__ acc2, int N, int g0, int g1)
{
    int lane = threadIdx.x & 63;
    int wv = threadIdx.x >> 6;
    int stride = gridDim.x*4;
    const float NEG = -__builtin_inff();
    for (int node = blockIdx.x*4 + wv; node < N; node += stride) {
        float add = 0.f;
        bool any = false;
        for (int r = g0; r < g1; ++r) {
            int s = rfl(off8[node*8 + r]);
            int e = rfl(off8[node*8 + r + 1]);
            if (s == e) continue;
            any = true;
            const unsigned short* Up = Ubf + (size_t)(r - g0)*plane;
            float mx = NEG;
            int i = s;
            for (; i + 4 <= e; i += 4) {
                int sx[4];
                #pragma unroll
                for (int u = 0; u < 4; ++u) sx[u] = rfl(srec[i+u].x) & 0xFFFFFF;
                float vg[4];
                #pragma unroll
                for (int u = 0; u < 4; ++u) vg[u] = bf2f(Up[(size_t)sx[u]*64 + lane]);
                mx = fmaxf(mx, fmaxf(fmaxf(vg[0], vg[1]), fmaxf(vg[2], vg[3])));
            }
            for (; i < e; ++i) {
                int sx = rfl(srec[i].x) & 0xFFFFFF;
                mx = fmaxf(mx, bf2f(Up[(size_t)sx*64 + lane]));
            }
            add += mx;
        }
        if (any) acc2[(size_t)node*64 + lane] += add;
    }
}

// ---------- head ----------
__global__ __launch_bounds__(64) void k_final(
    const float* __restrict__ acc2, const float* __restrict__ omega,
    const float* __restrict__ Wo, const float* __restrict__ bo,
    const float* __restrict__ Wagg, const float* __restrict__ bagg,
    const float* __restrict__ Wc, const float* __restrict__ bc,
    float* __restrict__ out)
{
    int i = blockIdx.x, j = threadIdx.x;
    __shared__ __align__(16) float cS[128];
    float om0 = omega[2*i], om1 = omega[2*i+1];
    float oj = fmaxf(fmaf(om1, Wo[64+j], fmaf(om0, Wo[j], bo[j])), 0.f);
    float h2 = fmaxf(acc2[(size_t)i*64 + j], 0.f);
    cS[j] = h2;
    cS[64 + j] = oj;
    __syncthreads();
    float t = bagg[j];
    const float4* c4 = (const float4*)cS;
    #pragma unroll
    for (int c = 0; c < 32; ++c) {
        float4 f = c4[c];
        t = fmaf(f.x, Wagg[(4*c+0)*64+j], t);
        t = fmaf(f.y, Wagg[(4*c+1)*64+j], t);
        t = fmaf(f.z, Wagg[(4*c+2)*64+j], t);
        t = fmaf(f.w, Wagg[(4*c+3)*64+j], t);
    }
    t = fmaxf(t, 0.f);
    float part = t * Wc[j];
    #pragma unroll
    for (int off = 32; off; off >>= 1) part += __shfl_xor(part, off);
    if (j == 0) out[i] = tanhf(part + bc[0]) * 5.0f;
}

extern "C" void kernel_launch(void* const* d_in, const int* in_sizes, int n_in,
                              void* d_out, int out_size, void* d_ws, size_t ws_size,
                              hipStream_t stream)
{
    const float* x      = (const float*)d_in[0];
    const int*   ei     = (const int*)d_in[1];
    const float* ea     = (const float*)d_in[2];
    const int*   et     = (const int*)d_in[3];
    const float* omega  = (const float*)d_in[4];
    const float* Wn     = (const float*)d_in[5];
    const float* bn     = (const float*)d_in[6];
    const float* We     = (const float*)d_in[7];
    const float* be     = (const float*)d_in[8];
    const float* Wo     = (const float*)d_in[9];
    const float* bo     = (const float*)d_in[10];
    const float* W1     = (const float*)d_in[11];
    const float* Wroot1 = (const float*)d_in[12];
    const float* b1     = (const float*)d_in[13];
    const float* W2     = (const float*)d_in[14];
    const float* Wroot2 = (const float*)d_in[15];
    const float* b2     = (const float*)d_in[16];
    const float* Wagg   = (const float*)d_in[17];
    const float* bagg   = (const float*)d_in[18];
    const float* Wc     = (const float*)d_in[19];
    const float* bc     = (const float*)d_in[20];
    int N = in_sizes[0] / 3;
    int E = in_sizes[3];
    float* out = (float*)d_out;

    int K8 = N*8;
    int nb = (K8 + SCHUNK - 1)/SCHUNK;

    // ---- workspace layout: fixed ~74 MB + adaptive bf16 plane pool ----
    char* pp = (char*)d_ws;
    float* nbuf   = (float*)pp;  pp += (size_t)N*64*4;      // n; reused as acc2
    float* acc1   = (float*)pp;  pp += (size_t)N*64*4;      // acc1 -> h
    int2*  srec   = (int2*)pp;   pp += (size_t)E*8;         // (dst,rel)-sorted packed edges
    int*   deg8   = (int*)pp;    pp += (size_t)K8*4;
    int*   off8   = (int*)pp;    pp += (size_t)(K8+1)*4;
    int*   cursor = (int*)pp;    pp += (size_t)K8*4;
    int*   bsum   = (int*)pp;    pp += (size_t)nb*4;
    unsigned short* wpk = (unsigned short*)pp; pp += (size_t)32*4*64*16*2;  // 256 KB
    size_t off = ((size_t)(pp - (char*)d_ws) + 255) & ~(size_t)255;
    size_t planeElems = (size_t)N*64;
    size_t avail = (ws_size > off) ? (ws_size - off) : 0;
    int G = (int)(avail / (planeElems*2));                  // bf16 planes
    if (G > 8) G = 8;
    if (G < 1) G = 1;
    unsigned short* Vbf = (unsigned short*)((char*)d_ws + off);
    float* acc2 = nbuf;

    k_encoder<<<N, 64, 0, stream>>>(x, Wn, bn, Wroot1, b1, nbuf, acc1);
    hipMemsetAsync(deg8, 0, (size_t)K8*4, stream);
    k_histd<<<(E + 255)/256, 256, 0, stream>>>(ei, et, deg8, E);
    k_bsum<<<nb, 256, 0, stream>>>(deg8, bsum, K8);
    k_bscan<<<1, 256, 0, stream>>>(bsum, nb);
    k_bapply<<<nb, 256, 0, stream>>>(deg8, bsum, off8, cursor, K8);
    k_scatd<<<(E + 255)/256, 256, 0, stream>>>(ei, ea, et, cursor, srec, E);
    k_wpack<<<128, 64, 0, stream>>>(W1, W2, wpk);

    int gblocks = (N + 63)/64;
    int aggBlocks = 4096;
    // ---- layer 1 ----
    int Gc1 = (G < 8) ? G : 8;
    k_vgemmB<<<gblocks, 256, 0, stream>>>(nbuf, wpk, 0, 0, Gc1, Vbf, planeElems, N);
    k_agg1e<<<aggBlocks, 256, 0, stream>>>(srec, off8, Vbf, planeElems, W1, We, be,
                                           acc1, N, Gc1);
    for (int g0 = Gc1; g0 < 8; g0 += G) {
        int Gc = (8 - g0 < G) ? (8 - g0) : G;
        k_vgemmB<<<gblocks, 256, 0, stream>>>(nbuf, wpk, 0, g0, Gc, Vbf, planeElems, N);
        k_agg1v<<<aggBlocks, 256, 0, stream>>>(srec, off8, Vbf, planeElems,
                                               acc1, N, g0, g0 + Gc);
    }
    k_hrow<<<N, 64, 0, stream>>>(acc1, acc2, Wroot2, b2);
    // ---- layer 2 ----
    for (int g0 = 0; g0 < 8; g0 += G) {
        int Gc = (8 - g0 < G) ? (8 - g0) : G;
        k_vgemmB<<<gblocks, 256, 0, stream>>>(acc1, wpk, 16, g0, Gc, Vbf, planeElems, N);
        k_agg2<<<aggBlocks, 256, 0, stream>>>(srec, off8, Vbf, planeElems,
                                              acc2, N, g0, g0 + Gc);
    }
    k_final<<<N, 64, 0, stream>>>(acc2, omega, Wo, bo, Wagg, bagg, Wc, bc, out);
}

// Round 13
// 881.221 us; speedup vs baseline: 1.0662x; 1.0662x over previous
//
#include <hip/hip_runtime.h>
#include <cmath>

typedef __attribute__((ext_vector_type(8))) short short8;
typedef __attribute__((ext_vector_type(4))) float floatx4;

// ---------- helpers ----------
__device__ __forceinline__ unsigned short rnbf(float f) {
    unsigned u = __float_as_uint(f);
    u += 0x7fffu + ((u >> 16) & 1u);
    return (unsigned short)(u >> 16);
}
__device__ __forceinline__ float bf2f(unsigned short h) {
    return __uint_as_float(((unsigned)h) << 16);
}
__device__ __forceinline__ int rfl(int v) { return __builtin_amdgcn_readfirstlane(v); }

// ---------- K0: encoder. one wave per node ----------
__global__ __launch_bounds__(64) void k_encoder(
    const float* __restrict__ x,
    const float* __restrict__ Wn, const float* __restrict__ bn,
    const float* __restrict__ Wroot1, const float* __restrict__ b1,
    float* __restrict__ nbuf, float* __restrict__ acc1)
{
    int i = blockIdx.x;
    int j = threadIdx.x;
    __shared__ __align__(16) float nS[64];
    float x0 = x[3*i], x1 = x[3*i+1], x2 = x[3*i+2];
    float nj = fmaxf(fmaf(x2, Wn[128+j], fmaf(x1, Wn[64+j], fmaf(x0, Wn[j], bn[j]))), 0.f);
    size_t o64 = (size_t)i*64 + j;
    nbuf[o64] = nj;
    nS[j] = nj;
    __syncthreads();
    float acc = b1[j];
    const float4* n4 = (const float4*)nS;
    #pragma unroll
    for (int c = 0; c < 16; ++c) {
        float4 f = n4[c];
        acc = fmaf(f.x, Wroot1[(4*c+0)*64+j], acc);
        acc = fmaf(f.y, Wroot1[(4*c+1)*64+j], acc);
        acc = fmaf(f.z, Wroot1[(4*c+2)*64+j], acc);
        acc = fmaf(f.w, Wroot1[(4*c+3)*64+j], acc);
    }
    acc1[o64] = acc;
}

// ---------- (dst,rel)-key histogram ----------
__global__ void k_histd(const int* __restrict__ ei, const int* __restrict__ et,
                        int* __restrict__ deg8, int E)
{
    int e = blockIdx.x*blockDim.x + threadIdx.x;
    if (e < E) atomicAdd(&deg8[ei[E + e]*8 + et[e]], 1);
}

// ---------- counting-sort scan over K=N*8 keys ----------
#define SCHUNK 1024
__global__ void k_bsum(const int* __restrict__ deg, int* __restrict__ bsum, int K)
{
    __shared__ int s[256];
    int b = blockIdx.x, t = threadIdx.x;
    int base = b*SCHUNK;
    int v = 0;
    for (int k = t; k < SCHUNK; k += 256) { int i = base + k; v += (i < K) ? deg[i] : 0; }
    s[t] = v; __syncthreads();
    for (int o = 128; o; o >>= 1) { if (t < o) s[t] += s[t+o]; __syncthreads(); }
    if (t == 0) bsum[b] = s[0];
}
__global__ void k_bscan(int* __restrict__ bsum, int nb)
{
    __shared__ int ts[256];
    int t = threadIdx.x;
    int v[4]; int loc = 0;
    #pragma unroll
    for (int u = 0; u < 4; ++u) { int i = t*4+u; v[u] = (i < nb) ? bsum[i] : 0; loc += v[u]; }
    ts[t] = loc; __syncthreads();
    for (int o = 1; o < 256; o <<= 1) {
        int add = (t >= o) ? ts[t-o] : 0;
        __syncthreads();
        ts[t] += add;
        __syncthreads();
    }
    int excl = ts[t] - loc;
    #pragma unroll
    for (int u = 0; u < 4; ++u) {
        int i = t*4+u;
        if (i < nb) bsum[i] = excl;
        excl += v[u];
    }
}
__global__ void k_bapply(const int* __restrict__ deg, const int* __restrict__ bsum,
                         int* __restrict__ off, int* __restrict__ cursor, int K)
{
    __shared__ int ts[256];
    int b = blockIdx.x, t = threadIdx.x;
    int base = b*SCHUNK;
    int v[4]; int loc = 0;
    #pragma unroll
    for (int u = 0; u < 4; ++u) { int i = base + t*4 + u; v[u] = (i < K) ? deg[i] : 0; loc += v[u]; }
    ts[t] = loc; __syncthreads();
    for (int o = 1; o < 256; o <<= 1) {
        int add = (t >= o) ? ts[t-o] : 0;
        __syncthreads();
        ts[t] += add;
        __syncthreads();
    }
    int excl = ts[t] - loc + bsum[b];
    #pragma unroll
    for (int u = 0; u < 4; ++u) {
        int i = base + t*4 + u;
        if (i < K) { off[i] = excl; cursor[i] = excl; }
        excl += v[u];
        if (i == K-1) off[K] = excl;
    }
}

// ---------- scatter edges into (dst,rel)-sorted order, packed int2 ----------
// x = src | rel<<24 ; y = bf16(a0)<<16 | bf16(a1)
__global__ void k_scatd(const int* __restrict__ ei, const float* __restrict__ ea,
                        const int* __restrict__ et, int* __restrict__ cursor,
                        int2* __restrict__ srec, int E)
{
    int e = blockIdx.x*blockDim.x + threadIdx.x;
    if (e >= E) return;
    int rel = et[e];
    int key = ei[E + e]*8 + rel;
    int pos = atomicAdd(&cursor[key], 1);
    float2 a = ((const float2*)ea)[e];
    int xv = ei[e] | (rel << 24);
    int yv = ((int)rnbf(a.x) << 16) | (int)rnbf(a.y);
    srec[pos] = make_int2(xv, yv);
}

// ---------- pack weights into MFMA B-fragment order, split bf16 hi/lo ----------
// units: [0,16)=W1A rel=u>>1,ks=u&1 rows0..63 of W1; [16,32)=W2; [32,40)=W1B rows64..95
__global__ __launch_bounds__(64) void k_wpack(
    const float* __restrict__ W1, const float* __restrict__ W2,
    unsigned short* __restrict__ wpk)
{
    int unit = blockIdx.x >> 2;
    int jt = blockIdx.x & 3;
    int lane = threadIdx.x;
    const float* Wb;
    int kbase;
    if (unit < 16) {
        Wb = W1 + (size_t)(unit >> 1)*96*64;
        kbase = (unit & 1)*32;
    } else if (unit < 32) {
        Wb = W2 + (size_t)((unit - 16) >> 1)*64*64;
        kbase = ((unit - 16) & 1)*32;
    } else {
        Wb = W1 + (size_t)(unit - 32)*96*64;
        kbase = 64;
    }
    int j = jt*16 + (lane & 15);
    size_t base = (((size_t)unit*4 + jt)*64 + lane)*16;
    #pragma unroll
    for (int i = 0; i < 8; ++i) {
        int k = kbase + (lane >> 4)*8 + i;
        float f = Wb[(size_t)k*64 + j];
        unsigned short hi = rnbf(f);
        unsigned short lo = rnbf(f - bf2f(hi));
        wpk[base + i] = hi;
        wpk[base + 8 + i] = lo;
    }
}

// ---------- dense GEMM via MFMA split-bf16, bf16 output ----------
__global__ __launch_bounds__(256) void k_vgemmB(
    const float* __restrict__ F, const unsigned short* __restrict__ wpk,
    int unitBase, int g0, int Gc, unsigned short* __restrict__ Vbf,
    size_t plane, int N)
{
    int lane = threadIdx.x & 63;
    int wave = threadIdx.x >> 6;
    int n0 = blockIdx.x*64 + 16*wave;
    int m = lane & 15, q = lane >> 4;
    int node = n0 + m;
    if (node >= N) node = N - 1;
    const float4* Fr = (const float4*)(F + (size_t)node*64);
    short8 ah[2], al[2];
    #pragma unroll
    for (int ks = 0; ks < 2; ++ks) {
        float4 u0 = Fr[ks*8 + q*2];
        float4 u1 = Fr[ks*8 + q*2 + 1];
        float fv[8] = {u0.x,u0.y,u0.z,u0.w,u1.x,u1.y,u1.z,u1.w};
        #pragma unroll
        for (int i = 0; i < 8; ++i) {
            unsigned short hb = rnbf(fv[i]);
            ah[ks][i] = (short)hb;
            al[ks][i] = (short)rnbf(fv[i] - bf2f(hb));
        }
    }
    for (int p = 0; p < Gc; ++p) {
        int rel = g0 + p;
        floatx4 acc[4];
        #pragma unroll
        for (int jt = 0; jt < 4; ++jt) acc[jt] = (floatx4){0.f,0.f,0.f,0.f};
        #pragma unroll
        for (int ks = 0; ks < 2; ++ks) {
            int unit = unitBase + rel*2 + ks;
            #pragma unroll
            for (int jt = 0; jt < 4; ++jt) {
                const unsigned short* qp = wpk + (((size_t)unit*4 + jt)*64 + lane)*16;
                short8 bh = *(const short8*)qp;
                short8 bl = *(const short8*)(qp + 8);
                acc[jt] = __builtin_amdgcn_mfma_f32_16x16x32_bf16(ah[ks], bh, acc[jt], 0,0,0);
                acc[jt] = __builtin_amdgcn_mfma_f32_16x16x32_bf16(ah[ks], bl, acc[jt], 0,0,0);
                acc[jt] = __builtin_amdgcn_mfma_f32_16x16x32_bf16(al[ks], bh, acc[jt], 0,0,0);
            }
        }
        unsigned short* Vp = Vbf + (size_t)p*plane;
        #pragma unroll
        for (int jt = 0; jt < 4; ++jt) {
            #pragma unroll
            for (int t = 0; t < 4; ++t) {
                int row = n0 + q*4 + t;
                if (row < N) Vp[(size_t)row*64 + jt*16 + m] = rnbf(acc[jt][t]);
            }
        }
    }
}

// ---------- layer-1 pass 1: single srec sweep. V-gather rels [0,Gc) (8-batched)
// + e-sums for ALL rels into se[8] regs; Se stored to Sepool (dense e-GEMM later).
__global__ __launch_bounds__(256) void k_agg1e(
    const int2* __restrict__ srec, const int* __restrict__ off8,
    const unsigned short* __restrict__ Vbf, size_t plane,
    const float* __restrict__ We, const float* __restrict__ be,
    float* __restrict__ acc1, unsigned short* __restrict__ Sep, int N, int Gc)
{
    int lane = threadIdx.x & 63;
    int wv = threadIdx.x >> 6;
    float we0 = We[lane & 31], we1 = We[32 + (lane & 31)], bev = be[lane & 31];
    int stride = gridDim.x*4;
    for (int node = blockIdx.x*4 + wv; node < N; node += stride) {
        int o[9];
        #pragma unroll
        for (int r = 0; r < 9; ++r) o[r] = rfl(off8[node*8 + r]);
        float vsum = 0.f;
        float se[8];
        #pragma unroll
        for (int r = 0; r < 8; ++r) se[r] = 0.f;
        #pragma unroll
        for (int r = 0; r < 8; ++r) {
            int s = o[r], e = o[r+1];
            if (s == e) continue;                      // wave-uniform
            const unsigned short* Vp = Vbf + (size_t)r*plane;
            bool doV = (r < Gc);                       // wave-uniform
            float ev = 0.f;
            int i = s;
            for (; i + 8 <= e; i += 8) {
                int2 rr[8];
                #pragma unroll
                for (int u = 0; u < 8; ++u) rr[u] = srec[i+u];   // uniform broadcast
                if (doV) {
                    float vg[8];
                    #pragma unroll
                    for (int u = 0; u < 8; ++u) {
                        int sx = rfl(rr[u].x) & 0xFFFFFF;
                        vg[u] = bf2f(Vp[(size_t)sx*64 + lane]);  // 8 gathers in flight
                    }
                    vsum += ((vg[0]+vg[1])+(vg[2]+vg[3])) + ((vg[4]+vg[5])+(vg[6]+vg[7]));
                }
                #pragma unroll
                for (int u = 0; u < 8; ++u) {
                    unsigned ry = (unsigned)rr[u].y;
                    float a0 = __uint_as_float(ry & 0xFFFF0000u);
                    float a1 = __uint_as_float(ry << 16);
                    ev += fmaxf(fmaf(a1, we1, fmaf(a0, we0, bev)), 0.f);
                }
            }
            for (; i < e; ++i) {
                int2 rr = srec[i];
                if (doV) {
                    int sx = rfl(rr.x) & 0xFFFFFF;
                    vsum += bf2f(Vp[(size_t)sx*64 + lane]);
                }
                unsigned ry = (unsigned)rr.y;
                float a0 = __uint_as_float(ry & 0xFFFF0000u);
                float a1 = __uint_as_float(ry << 16);
                ev += fmaxf(fmaf(a1, we1, fmaf(a0, we0, bev)), 0.f);
            }
            se[r] = ev;
        }
        // Se store: layout [node][rel][32] bf16; lanes<32 carry se[2k], >=32 se[2k+1]
        // (e-rows are duplicated across wave halves, so upper lanes hold valid se[2k+1]).
        unsigned short* Sp = Sep + (size_t)node*256;
        #pragma unroll
        for (int k = 0; k < 4; ++k) {
            float v = (lane < 32) ? se[2*k] : se[2*k+1];
            Sp[k*64 + lane] = rnbf(v);                 // 4× coalesced 128B stores
        }
        if (o[0] != o[8]) acc1[(size_t)node*64 + lane] += vsum;
    }
}

// ---------- layer-1 pass 2+: run-wise V-gather only, rels [g0,g1) ----------
__global__ __launch_bounds__(256) void k_agg1v(
    const int2* __restrict__ srec, const int* __restrict__ off8,
    const unsigned short* __restrict__ Vbf, size_t plane,
    float* __restrict__ acc1, int N, int g0, int g1)
{
    int lane = threadIdx.x & 63;
    int wv = threadIdx.x >> 6;
    int stride = gridDim.x*4;
    for (int node = blockIdx.x*4 + wv; node < N; node += stride) {
        float vsum = 0.f;
        bool any = false;
        for (int r = g0; r < g1; ++r) {
            int s = rfl(off8[node*8 + r]);
            int e = rfl(off8[node*8 + r + 1]);
            if (s == e) continue;
            any = true;
            const unsigned short* Vp = Vbf + (size_t)(r - g0)*plane;
            int i = s;
            for (; i + 8 <= e; i += 8) {
                int sx[8];
                #pragma unroll
                for (int u = 0; u < 8; ++u) sx[u] = rfl(srec[i+u].x) & 0xFFFFFF;
                float vg[8];
                #pragma unroll
                for (int u = 0; u < 8; ++u) vg[u] = bf2f(Vp[(size_t)sx[u]*64 + lane]);
                vsum += ((vg[0]+vg[1])+(vg[2]+vg[3])) + ((vg[4]+vg[5])+(vg[6]+vg[7]));
            }
            for (; i < e; ++i) {
                int sx = rfl(srec[i].x) & 0xFFFFFF;
                vsum += bf2f(Vp[(size_t)sx*64 + lane]);
            }
        }
        if (any) acc1[(size_t)node*64 + lane] += vsum;
    }
}

// ---------- Se GEMM via MFMA (Se bf16 exact): acc1 += sum_r Se[:,r,:] @ W1B[r] ----------
__global__ __launch_bounds__(256) void k_segemm(
    const unsigned short* __restrict__ Sep, const unsigned short* __restrict__ wpk,
    float* __restrict__ acc1, int N)
{
    int lane = threadIdx.x & 63;
    int wave = threadIdx.x >> 6;
    int n0 = blockIdx.x*64 + 16*wave;
    int m = lane & 15, q = lane >> 4;
    int node = n0 + m;
    if (node >= N) node = N - 1;
    floatx4 acc[4];
    #pragma unroll
    for (int jt = 0; jt < 4; ++jt) acc[jt] = (floatx4){0.f,0.f,0.f,0.f};
    for (int rel = 0; rel < 8; ++rel) {
        short8 ah = *(const short8*)(Sep + (size_t)node*256 + rel*32 + q*8);
        int unit = 32 + rel;
        #pragma unroll
        for (int jt = 0; jt < 4; ++jt) {
            const unsigned short* qp = wpk + (((size_t)unit*4 + jt)*64 + lane)*16;
            short8 bh = *(const short8*)qp;
            short8 bl = *(const short8*)(qp + 8);
            acc[jt] = __builtin_amdgcn_mfma_f32_16x16x32_bf16(ah, bh, acc[jt], 0,0,0);
            acc[jt] = __builtin_amdgcn_mfma_f32_16x16x32_bf16(ah, bl, acc[jt], 0,0,0);
        }
    }
    #pragma unroll
    for (int jt = 0; jt < 4; ++jt) {
        #pragma unroll
        for (int t = 0; t < 4; ++t) {
            int row = n0 + q*4 + t;
            if (row < N) acc1[(size_t)row*64 + jt*16 + m] += acc[jt][t];
        }
    }
}

// ---------- fused relu + root2: acc1->h in place; acc2 = h@Wroot2+b2 ----------
__global__ __launch_bounds__(64) void k_hrow(
    float* __restrict__ acc1, float* __restrict__ acc2,
    const float* __restrict__ Wroot2, const float* __restrict__ b2)
{
    int i = blockIdx.x, j = threadIdx.x;
    __shared__ __align__(16) float hS[64];
    size_t o64 = (size_t)i*64 + j;
    float h = fmaxf(acc1[o64], 0.f);
    acc1[o64] = h;
    hS[j] = h;
    __syncthreads();
    float acc = b2[j];
    const float4* h4 = (const float4*)hS;
    #pragma unroll
    for (int c = 0; c < 16; ++c) {
        float4 f = h4[c];
        acc = fmaf(f.x, Wroot2[(4*c+0)*64+j], acc);
        acc = fmaf(f.y, Wroot2[(4*c+1)*64+j], acc);
        acc = fmaf(f.z, Wroot2[(4*c+2)*64+j], acc);
        acc = fmaf(f.w, Wroot2[(4*c+3)*64+j], acc);
    }
    acc2[o64] = acc;
}

// ---------- layer-2: run-wise max per (node,rel), rels [g0,g1), 8-batched ----------
__global__ __launch_bounds__(256) void k_agg2(
    const int2* __restrict__ srec, const int* __restrict__ off8,
    const unsigned short* __restrict__ Ubf, size_t plane,
    float* __restrict__ acc2, int N, int g0, int g1)
{
    int lane = threadIdx.x & 63;
    int wv = threadIdx.x >> 6;
    int stride = gridDim.x*4;
    const float NEG = -__builtin_inff();
    for (int node = blockIdx.x*4 + wv; node < N; node += stride) {
        float add = 0.f;
        bool any = false;
        for (int r = g0; r < g1; ++r) {
            int s = rfl(off8[node*8 + r]);
            int e = rfl(off8[node*8 + r + 1]);
            if (s == e) continue;
            any = true;
            const unsigned short* Up = Ubf + (size_t)(r - g0)*plane;
            float mx = NEG;
            int i = s;
            for (; i + 8 <= e; i += 8) {
                int sx[8];
                #pragma unroll
                for (int u = 0; u < 8; ++u) sx[u] = rfl(srec[i+u].x) & 0xFFFFFF;
                float vg[8];
                #pragma unroll
                for (int u = 0; u < 8; ++u) vg[u] = bf2f(Up[(size_t)sx[u]*64 + lane]);
                float m01 = fmaxf(vg[0], vg[1]), m23 = fmaxf(vg[2], vg[3]);
                float m45 = fmaxf(vg[4], vg[5]), m67 = fmaxf(vg[6], vg[7]);
                mx = fmaxf(mx, fmaxf(fmaxf(m01, m23), fmaxf(m45, m67)));
            }
            for (; i < e; ++i) {
                int sx = rfl(srec[i].x) & 0xFFFFFF;
                mx = fmaxf(mx, bf2f(Up[(size_t)sx*64 + lane]));
            }
            add += mx;
        }
        if (any) acc2[(size_t)node*64 + lane] += add;
    }
}

// ---------- head ----------
__global__ __launch_bounds__(64) void k_final(
    const float* __restrict__ acc2, const float* __restrict__ omega,
    const float* __restrict__ Wo, const float* __restrict__ bo,
    const float* __restrict__ Wagg, const float* __restrict__ bagg,
    const float* __restrict__ Wc, const float* __restrict__ bc,
    float* __restrict__ out)
{
    int i = blockIdx.x, j = threadIdx.x;
    __shared__ __align__(16) float cS[128];
    float om0 = omega[2*i], om1 = omega[2*i+1];
    float oj = fmaxf(fmaf(om1, Wo[64+j], fmaf(om0, Wo[j], bo[j])), 0.f);
    float h2 = fmaxf(acc2[(size_t)i*64 + j], 0.f);
    cS[j] = h2;
    cS[64 + j] = oj;
    __syncthreads();
    float t = bagg[j];
    const float4* c4 = (const float4*)cS;
    #pragma unroll
    for (int c = 0; c < 32; ++c) {
        float4 f = c4[c];
        t = fmaf(f.x, Wagg[(4*c+0)*64+j], t);
        t = fmaf(f.y, Wagg[(4*c+1)*64+j], t);
        t = fmaf(f.z, Wagg[(4*c+2)*64+j], t);
        t = fmaf(f.w, Wagg[(4*c+3)*64+j], t);
    }
    t = fmaxf(t, 0.f);
    float part = t * Wc[j];
    #pragma unroll
    for (int off = 32; off; off >>= 1) part += __shfl_xor(part, off);
    if (j == 0) out[i] = tanhf(part + bc[0]) * 5.0f;
}

extern "C" void kernel_launch(void* const* d_in, const int* in_sizes, int n_in,
                              void* d_out, int out_size, void* d_ws, size_t ws_size,
                              hipStream_t stream)
{
    const float* x      = (const float*)d_in[0];
    const int*   ei     = (const int*)d_in[1];
    const float* ea     = (const float*)d_in[2];
    const int*   et     = (const int*)d_in[3];
    const float* omega  = (const float*)d_in[4];
    const float* Wn     = (const float*)d_in[5];
    const float* bn     = (const float*)d_in[6];
    const float* We     = (const float*)d_in[7];
    const float* be     = (const float*)d_in[8];
    const float* Wo     = (const float*)d_in[9];
    const float* bo     = (const float*)d_in[10];
    const float* W1     = (const float*)d_in[11];
    const float* Wroot1 = (const float*)d_in[12];
    const float* b1     = (const float*)d_in[13];
    const float* W2     = (const float*)d_in[14];
    const float* Wroot2 = (const float*)d_in[15];
    const float* b2     = (const float*)d_in[16];
    const float* Wagg   = (const float*)d_in[17];
    const float* bagg   = (const float*)d_in[18];
    const float* Wc     = (const float*)d_in[19];
    const float* bc     = (const float*)d_in[20];
    int N = in_sizes[0] / 3;
    int E = in_sizes[3];
    float* out = (float*)d_out;

    int K8 = N*8;
    int nb = (K8 + SCHUNK - 1)/SCHUNK;

    // ---- workspace layout: every carve 256B-aligned ----
    #define ALIGN256(p) ((char*)(((size_t)(p) + 255) & ~(size_t)255))
    char* pp = (char*)d_ws;
    float* nbuf   = (float*)pp;  pp = ALIGN256(pp + (size_t)N*64*4);     // n; reused as acc2
    float* acc1   = (float*)pp;  pp = ALIGN256(pp + (size_t)N*64*4);     // acc1 -> h
    int2*  srec   = (int2*)pp;   pp = ALIGN256(pp + (size_t)E*8);        // (dst,rel)-sorted edges
    int*   deg8   = (int*)pp;    pp = ALIGN256(pp + (size_t)K8*4);
    int*   off8   = (int*)pp;    pp = ALIGN256(pp + (size_t)(K8+1)*4);
    int*   cursor = (int*)pp;    pp = ALIGN256(pp + (size_t)K8*4);
    int*   bsum   = (int*)pp;    pp = ALIGN256(pp + (size_t)nb*4);
    unsigned short* wpk = (unsigned short*)pp;
    pp = ALIGN256(pp + (size_t)40*4*64*16*2);                            // 320 KB
    unsigned short* Sepool = (unsigned short*)pp;
    pp = ALIGN256(pp + (size_t)N*256*2);                                 // [N][8][32] bf16, 51 MB
    size_t off = (size_t)(pp - (char*)d_ws);
    size_t planeElems = (size_t)N*64;
    size_t avail = (ws_size > off) ? (ws_size - off) : 0;
    int G = (int)(avail / (planeElems*2));                               // bf16 planes
    if (G > 8) G = 8;
    if (G < 1) G = 1;
    unsigned short* Vbf = (unsigned short*)pp;
    float* acc2 = nbuf;

    k_encoder<<<N, 64, 0, stream>>>(x, Wn, bn, Wroot1, b1, nbuf, acc1);
    hipMemsetAsync(deg8, 0, (size_t)K8*4, stream);
    k_histd<<<(E + 255)/256, 256, 0, stream>>>(ei, et, deg8, E);
    k_bsum<<<nb, 256, 0, stream>>>(deg8, bsum, K8);
    k_bscan<<<1, 256, 0, stream>>>(bsum, nb);
    k_bapply<<<nb, 256, 0, stream>>>(deg8, bsum, off8, cursor, K8);
    k_scatd<<<(E + 255)/256, 256, 0, stream>>>(ei, ea, et, cursor, srec, E);
    k_wpack<<<160, 64, 0, stream>>>(W1, W2, wpk);

    int gblocks = (N + 63)/64;
    int aggBlocks = 4096;
    // ---- layer 1 ----
    int Gc1 = (G < 8) ? G : 8;
    k_vgemmB<<<gblocks, 256, 0, stream>>>(nbuf, wpk, 0, 0, Gc1, Vbf, planeElems, N);
    k_agg1e<<<aggBlocks, 256, 0, stream>>>(srec, off8, Vbf, planeElems, We, be,
                                           acc1, Sepool, N, Gc1);
    for (int g0 = Gc1; g0 < 8; g0 += G) {
        int Gc = (8 - g0 < G) ? (8 - g0) : G;
        k_vgemmB<<<gblocks, 256, 0, stream>>>(nbuf, wpk, 0, g0, Gc, Vbf, planeElems, N);
        k_agg1v<<<aggBlocks, 256, 0, stream>>>(srec, off8, Vbf, planeElems,
                                               acc1, N, g0, g0 + Gc);
    }
    k_segemm<<<gblocks, 256, 0, stream>>>(Sepool, wpk, acc1, N);
    k_hrow<<<N, 64, 0, stream>>>(acc1, acc2, Wroot2, b2);
    // ---- layer 2 ----
    for (int g0 = 0; g0 < 8; g0 += G) {
        int Gc = (8 - g0 < G) ? (8 - g0) : G;
        k_vgemmB<<<gblocks, 256, 0, stream>>>(acc1, wpk, 16, g0, Gc, Vbf, planeElems, N);
        k_agg2<<<aggBlocks, 256, 0, stream>>>(srec, off8, Vbf, planeElems,
                                              acc2, N, g0, g0 + Gc);
    }
    k_final<<<N, 64, 0, stream>>>(acc2, omega, Wo, bo, Wagg, bagg, Wc, bc, out);
}

// Round 14
// 856.637 us; speedup vs baseline: 1.0968x; 1.0287x over previous
//
#include <hip/hip_runtime.h>
#include <cmath>

typedef __attribute__((ext_vector_type(8))) short short8;
typedef __attribute__((ext_vector_type(4))) float floatx4;

// ---------- helpers ----------
__device__ __forceinline__ unsigned short rnbf(float f) {
    unsigned u = __float_as_uint(f);
    u += 0x7fffu + ((u >> 16) & 1u);
    return (unsigned short)(u >> 16);
}
__device__ __forceinline__ float bf2f(unsigned short h) {
    return __uint_as_float(((unsigned)h) << 16);
}
__device__ __forceinline__ int rfl(int v) { return __builtin_amdgcn_readfirstlane(v); }
__device__ __forceinline__ float eAct(unsigned ry, float we0, float we1, float bev) {
    float a0 = __uint_as_float(ry & 0xFFFF0000u);
    float a1 = __uint_as_float(ry << 16);
    return fmaxf(fmaf(a1, we1, fmaf(a0, we0, bev)), 0.f);
}

// ---------- K0: encoder. 4 nodes/block, wave = node ----------
__global__ __launch_bounds__(256) void k_encoder(
    const float* __restrict__ x,
    const float* __restrict__ Wn, const float* __restrict__ bn,
    const float* __restrict__ Wroot1, const float* __restrict__ b1,
    float* __restrict__ nbuf, float* __restrict__ acc1, int N)
{
    __shared__ __align__(16) float nS[4][64];
    int j = threadIdx.x & 63;
    int wv = threadIdx.x >> 6;
    int i = blockIdx.x*4 + wv;
    if (i >= N) return;
    float x0 = x[3*i], x1 = x[3*i+1], x2 = x[3*i+2];
    float nj = fmaxf(fmaf(x2, Wn[128+j], fmaf(x1, Wn[64+j], fmaf(x0, Wn[j], bn[j]))), 0.f);
    size_t o64 = (size_t)i*64 + j;
    nbuf[o64] = nj;
    nS[wv][j] = nj;                                   // same-wave LDS, no barrier
    float acc = b1[j];
    const float4* n4 = (const float4*)&nS[wv][0];
    #pragma unroll
    for (int c = 0; c < 16; ++c) {
        float4 f = n4[c];
        acc = fmaf(f.x, Wroot1[(4*c+0)*64+j], acc);
        acc = fmaf(f.y, Wroot1[(4*c+1)*64+j], acc);
        acc = fmaf(f.z, Wroot1[(4*c+2)*64+j], acc);
        acc = fmaf(f.w, Wroot1[(4*c+3)*64+j], acc);
    }
    acc1[o64] = acc;
}

// ---------- (dst,rel)-key histogram ----------
__global__ void k_histd(const int* __restrict__ ei, const int* __restrict__ et,
                        int* __restrict__ deg8, int E)
{
    int e = blockIdx.x*blockDim.x + threadIdx.x;
    if (e < E) atomicAdd(&deg8[ei[E + e]*8 + et[e]], 1);
}

// ---------- counting-sort scan over K=N*8 keys ----------
#define SCHUNK 1024
__global__ void k_bsum(const int* __restrict__ deg, int* __restrict__ bsum, int K)
{
    __shared__ int s[256];
    int b = blockIdx.x, t = threadIdx.x;
    int base = b*SCHUNK;
    int v = 0;
    for (int k = t; k < SCHUNK; k += 256) { int i = base + k; v += (i < K) ? deg[i] : 0; }
    s[t] = v; __syncthreads();
    for (int o = 128; o; o >>= 1) { if (t < o) s[t] += s[t+o]; __syncthreads(); }
    if (t == 0) bsum[b] = s[0];
}
__global__ void k_bscan(int* __restrict__ bsum, int nb)
{
    __shared__ int ts[256];
    int t = threadIdx.x;
    int v[4]; int loc = 0;
    #pragma unroll
    for (int u = 0; u < 4; ++u) { int i = t*4+u; v[u] = (i < nb) ? bsum[i] : 0; loc += v[u]; }
    ts[t] = loc; __syncthreads();
    for (int o = 1; o < 256; o <<= 1) {
        int add = (t >= o) ? ts[t-o] : 0;
        __syncthreads();
        ts[t] += add;
        __syncthreads();
    }
    int excl = ts[t] - loc;
    #pragma unroll
    for (int u = 0; u < 4; ++u) {
        int i = t*4+u;
        if (i < nb) bsum[i] = excl;
        excl += v[u];
    }
}
__global__ void k_bapply(const int* __restrict__ deg, const int* __restrict__ bsum,
                         int* __restrict__ off, int* __restrict__ cursor, int K)
{
    __shared__ int ts[256];
    int b = blockIdx.x, t = threadIdx.x;
    int base = b*SCHUNK;
    int v[4]; int loc = 0;
    #pragma unroll
    for (int u = 0; u < 4; ++u) { int i = base + t*4 + u; v[u] = (i < K) ? deg[i] : 0; loc += v[u]; }
    ts[t] = loc; __syncthreads();
    for (int o = 1; o < 256; o <<= 1) {
        int add = (t >= o) ? ts[t-o] : 0;
        __syncthreads();
        ts[t] += add;
        __syncthreads();
    }
    int excl = ts[t] - loc + bsum[b];
    #pragma unroll
    for (int u = 0; u < 4; ++u) {
        int i = base + t*4 + u;
        if (i < K) { off[i] = excl; cursor[i] = excl; }
        excl += v[u];
        if (i == K-1) off[K] = excl;
    }
}

// ---------- scatter edges into (dst,rel)-sorted order, packed int2 ----------
// x = src | rel<<24 ; y = bf16(a0)<<16 | bf16(a1)
__global__ void k_scatd(const int* __restrict__ ei, const float* __restrict__ ea,
                        const int* __restrict__ et, int* __restrict__ cursor,
                        int2* __restrict__ srec, int E)
{
    int e = blockIdx.x*blockDim.x + threadIdx.x;
    if (e >= E) return;
    int rel = et[e];
    int key = ei[E + e]*8 + rel;
    int pos = atomicAdd(&cursor[key], 1);
    float2 a = ((const float2*)ea)[e];
    int xv = ei[e] | (rel << 24);
    int yv = ((int)rnbf(a.x) << 16) | (int)rnbf(a.y);
    srec[pos] = make_int2(xv, yv);
}

// ---------- pack weights into MFMA B-fragment order, split bf16 hi/lo ----------
// units: [0,16)=W1A rel=u>>1,ks=u&1 rows0..63 of W1; [16,32)=W2; [32,40)=W1B rows64..95
__global__ __launch_bounds__(64) void k_wpack(
    const float* __restrict__ W1, const float* __restrict__ W2,
    unsigned short* __restrict__ wpk)
{
    int unit = blockIdx.x >> 2;
    int jt = blockIdx.x & 3;
    int lane = threadIdx.x;
    const float* Wb;
    int kbase;
    if (unit < 16) {
        Wb = W1 + (size_t)(unit >> 1)*96*64;
        kbase = (unit & 1)*32;
    } else if (unit < 32) {
        Wb = W2 + (size_t)((unit - 16) >> 1)*64*64;
        kbase = ((unit - 16) & 1)*32;
    } else {
        Wb = W1 + (size_t)(unit - 32)*96*64;
        kbase = 64;
    }
    int j = jt*16 + (lane & 15);
    size_t base = (((size_t)unit*4 + jt)*64 + lane)*16;
    #pragma unroll
    for (int i = 0; i < 8; ++i) {
        int k = kbase + (lane >> 4)*8 + i;
        float f = Wb[(size_t)k*64 + j];
        unsigned short hi = rnbf(f);
        unsigned short lo = rnbf(f - bf2f(hi));
        wpk[base + i] = hi;
        wpk[base + 8 + i] = lo;
    }
}

// ---------- dense GEMM via MFMA split-bf16, bf16 output ----------
__global__ __launch_bounds__(256) void k_vgemmB(
    const float* __restrict__ F, const unsigned short* __restrict__ wpk,
    int unitBase, int g0, int Gc, unsigned short* __restrict__ Vbf,
    size_t plane, int N)
{
    int lane = threadIdx.x & 63;
    int wave = threadIdx.x >> 6;
    int n0 = blockIdx.x*64 + 16*wave;
    int m = lane & 15, q = lane >> 4;
    int node = n0 + m;
    if (node >= N) node = N - 1;
    const float4* Fr = (const float4*)(F + (size_t)node*64);
    short8 ah[2], al[2];
    #pragma unroll
    for (int ks = 0; ks < 2; ++ks) {
        float4 u0 = Fr[ks*8 + q*2];
        float4 u1 = Fr[ks*8 + q*2 + 1];
        float fv[8] = {u0.x,u0.y,u0.z,u0.w,u1.x,u1.y,u1.z,u1.w};
        #pragma unroll
        for (int i = 0; i < 8; ++i) {
            unsigned short hb = rnbf(fv[i]);
            ah[ks][i] = (short)hb;
            al[ks][i] = (short)rnbf(fv[i] - bf2f(hb));
        }
    }
    for (int p = 0; p < Gc; ++p) {
        int rel = g0 + p;
        floatx4 acc[4];
        #pragma unroll
        for (int jt = 0; jt < 4; ++jt) acc[jt] = (floatx4){0.f,0.f,0.f,0.f};
        #pragma unroll
        for (int ks = 0; ks < 2; ++ks) {
            int unit = unitBase + rel*2 + ks;
            #pragma unroll
            for (int jt = 0; jt < 4; ++jt) {
                const unsigned short* qp = wpk + (((size_t)unit*4 + jt)*64 + lane)*16;
                short8 bh = *(const short8*)qp;
                short8 bl = *(const short8*)(qp + 8);
                acc[jt] = __builtin_amdgcn_mfma_f32_16x16x32_bf16(ah[ks], bh, acc[jt], 0,0,0);
                acc[jt] = __builtin_amdgcn_mfma_f32_16x16x32_bf16(ah[ks], bl, acc[jt], 0,0,0);
                acc[jt] = __builtin_amdgcn_mfma_f32_16x16x32_bf16(al[ks], bh, acc[jt], 0,0,0);
            }
        }
        unsigned short* Vp = Vbf + (size_t)p*plane;
        #pragma unroll
        for (int jt = 0; jt < 4; ++jt) {
            #pragma unroll
            for (int t = 0; t < 4; ++t) {
                int row = n0 + q*4 + t;
                if (row < N) Vp[(size_t)row*64 + jt*16 + m] = rnbf(acc[jt][t]);
            }
        }
    }
}

// ---------- layer-1 pass 1: single srec sweep, fully scalarized (no LDS promotion).
__global__ __launch_bounds__(256) void k_agg1e(
    const int2* __restrict__ srec, const int* __restrict__ off8,
    const unsigned short* __restrict__ Vbf, size_t plane,
    const float* __restrict__ We, const float* __restrict__ be,
    float* __restrict__ acc1, unsigned short* __restrict__ Sep, int N, int Gc)
{
    int lane = threadIdx.x & 63;
    int wv = threadIdx.x >> 6;
    float we0 = We[lane & 31], we1 = We[32 + (lane & 31)], bev = be[lane & 31];
    int stride = gridDim.x*4;
    for (int node = blockIdx.x*4 + wv; node < N; node += stride) {
        int o0 = rfl(off8[node*8+0]), o1 = rfl(off8[node*8+1]), o2 = rfl(off8[node*8+2]);
        int o3 = rfl(off8[node*8+3]), o4 = rfl(off8[node*8+4]), o5 = rfl(off8[node*8+5]);
        int o6 = rfl(off8[node*8+6]), o7 = rfl(off8[node*8+7]), o8 = rfl(off8[node*8+8]);
        float vsum = 0.f;
        float se0=0,se1=0,se2=0,se3=0,se4=0,se5=0,se6=0,se7=0;
        #pragma unroll
        for (int r = 0; r < 8; ++r) {
            int s = (r==0)?o0:(r==1)?o1:(r==2)?o2:(r==3)?o3:(r==4)?o4:(r==5)?o5:(r==6)?o6:o7;
            int e = (r==0)?o1:(r==1)?o2:(r==2)?o3:(r==3)?o4:(r==4)?o5:(r==5)?o6:(r==6)?o7:o8;
            if (s == e) continue;                      // wave-uniform
            const unsigned short* Vp = Vbf + (size_t)r*plane;
            bool doV = (r < Gc);                       // wave-uniform
            float ev = 0.f;
            int i = s;
            for (; i + 8 <= e; i += 8) {
                int2 q0 = srec[i+0], q1 = srec[i+1], q2 = srec[i+2], q3 = srec[i+3];
                int2 q4 = srec[i+4], q5 = srec[i+5], q6 = srec[i+6], q7 = srec[i+7];
                if (doV) {
                    float v0 = bf2f(Vp[(size_t)(rfl(q0.x) & 0xFFFFFF)*64 + lane]);
                    float v1 = bf2f(Vp[(size_t)(rfl(q1.x) & 0xFFFFFF)*64 + lane]);
                    float v2 = bf2f(Vp[(size_t)(rfl(q2.x) & 0xFFFFFF)*64 + lane]);
                    float v3 = bf2f(Vp[(size_t)(rfl(q3.x) & 0xFFFFFF)*64 + lane]);
                    float v4 = bf2f(Vp[(size_t)(rfl(q4.x) & 0xFFFFFF)*64 + lane]);
                    float v5 = bf2f(Vp[(size_t)(rfl(q5.x) & 0xFFFFFF)*64 + lane]);
                    float v6 = bf2f(Vp[(size_t)(rfl(q6.x) & 0xFFFFFF)*64 + lane]);
                    float v7 = bf2f(Vp[(size_t)(rfl(q7.x) & 0xFFFFFF)*64 + lane]);
                    vsum += ((v0+v1)+(v2+v3)) + ((v4+v5)+(v6+v7));
                }
                ev += eAct((unsigned)q0.y, we0, we1, bev);
                ev += eAct((unsigned)q1.y, we0, we1, bev);
                ev += eAct((unsigned)q2.y, we0, we1, bev);
                ev += eAct((unsigned)q3.y, we0, we1, bev);
                ev += eAct((unsigned)q4.y, we0, we1, bev);
                ev += eAct((unsigned)q5.y, we0, we1, bev);
                ev += eAct((unsigned)q6.y, we0, we1, bev);
                ev += eAct((unsigned)q7.y, we0, we1, bev);
            }
            for (; i < e; ++i) {
                int2 qq = srec[i];
                if (doV) vsum += bf2f(Vp[(size_t)(rfl(qq.x) & 0xFFFFFF)*64 + lane]);
                ev += eAct((unsigned)qq.y, we0, we1, bev);
            }
            if (r == 0) se0 = ev;  if (r == 1) se1 = ev;
            if (r == 2) se2 = ev;  if (r == 3) se3 = ev;
            if (r == 4) se4 = ev;  if (r == 5) se5 = ev;
            if (r == 6) se6 = ev;  if (r == 7) se7 = ev;
        }
        // Se store: [node][rel][32] bf16; lanes<32 carry even rel, >=32 odd rel
        unsigned short* Sp = Sep + (size_t)node*256;
        Sp[0*64 + lane] = rnbf((lane < 32) ? se0 : se1);
        Sp[1*64 + lane] = rnbf((lane < 32) ? se2 : se3);
        Sp[2*64 + lane] = rnbf((lane < 32) ? se4 : se5);
        Sp[3*64 + lane] = rnbf((lane < 32) ? se6 : se7);
        if (o0 != o8) acc1[(size_t)node*64 + lane] += vsum;
    }
}

// ---------- layer-1 pass 2+: run-wise V-gather only, rels [g0,g1), scalarized ----------
__global__ __launch_bounds__(256) void k_agg1v(
    const int2* __restrict__ srec, const int* __restrict__ off8,
    const unsigned short* __restrict__ Vbf, size_t plane,
    float* __restrict__ acc1, int N, int g0, int g1)
{
    int lane = threadIdx.x & 63;
    int wv = threadIdx.x >> 6;
    int stride = gridDim.x*4;
    for (int node = blockIdx.x*4 + wv; node < N; node += stride) {
        float vsum = 0.f;
        bool any = false;
        for (int r = g0; r < g1; ++r) {
            int s = rfl(off8[node*8 + r]);
            int e = rfl(off8[node*8 + r + 1]);
            if (s == e) continue;
            any = true;
            const unsigned short* Vp = Vbf + (size_t)(r - g0)*plane;
            int i = s;
            for (; i + 8 <= e; i += 8) {
                int s0 = rfl(srec[i+0].x) & 0xFFFFFF, s1 = rfl(srec[i+1].x) & 0xFFFFFF;
                int s2 = rfl(srec[i+2].x) & 0xFFFFFF, s3 = rfl(srec[i+3].x) & 0xFFFFFF;
                int s4 = rfl(srec[i+4].x) & 0xFFFFFF, s5 = rfl(srec[i+5].x) & 0xFFFFFF;
                int s6 = rfl(srec[i+6].x) & 0xFFFFFF, s7 = rfl(srec[i+7].x) & 0xFFFFFF;
                float v0 = bf2f(Vp[(size_t)s0*64 + lane]), v1 = bf2f(Vp[(size_t)s1*64 + lane]);
                float v2 = bf2f(Vp[(size_t)s2*64 + lane]), v3 = bf2f(Vp[(size_t)s3*64 + lane]);
                float v4 = bf2f(Vp[(size_t)s4*64 + lane]), v5 = bf2f(Vp[(size_t)s5*64 + lane]);
                float v6 = bf2f(Vp[(size_t)s6*64 + lane]), v7 = bf2f(Vp[(size_t)s7*64 + lane]);
                vsum += ((v0+v1)+(v2+v3)) + ((v4+v5)+(v6+v7));
            }
            for (; i < e; ++i) {
                int sx = rfl(srec[i].x) & 0xFFFFFF;
                vsum += bf2f(Vp[(size_t)sx*64 + lane]);
            }
        }
        if (any) acc1[(size_t)node*64 + lane] += vsum;
    }
}

// ---------- Se GEMM via MFMA (Se bf16 exact): acc1 += sum_r Se[:,r,:] @ W1B[r] ----------
__global__ __launch_bounds__(256) void k_segemm(
    const unsigned short* __restrict__ Sep, const unsigned short* __restrict__ wpk,
    float* __restrict__ acc1, int N)
{
    int lane = threadIdx.x & 63;
    int wave = threadIdx.x >> 6;
    int n0 = blockIdx.x*64 + 16*wave;
    int m = lane & 15, q = lane >> 4;
    int node = n0 + m;
    if (node >= N) node = N - 1;
    floatx4 acc[4];
    #pragma unroll
    for (int jt = 0; jt < 4; ++jt) acc[jt] = (floatx4){0.f,0.f,0.f,0.f};
    for (int rel = 0; rel < 8; ++rel) {
        short8 ah = *(const short8*)(Sep + (size_t)node*256 + rel*32 + q*8);
        int unit = 32 + rel;
        #pragma unroll
        for (int jt = 0; jt < 4; ++jt) {
            const unsigned short* qp = wpk + (((size_t)unit*4 + jt)*64 + lane)*16;
            short8 bh = *(const short8*)qp;
            short8 bl = *(const short8*)(qp + 8);
            acc[jt] = __builtin_amdgcn_mfma_f32_16x16x32_bf16(ah, bh, acc[jt], 0,0,0);
            acc[jt] = __builtin_amdgcn_mfma_f32_16x16x32_bf16(ah, bl, acc[jt], 0,0,0);
        }
    }
    #pragma unroll
    for (int jt = 0; jt < 4; ++jt) {
        #pragma unroll
        for (int t = 0; t < 4; ++t) {
            int row = n0 + q*4 + t;
            if (row < N) acc1[(size_t)row*64 + jt*16 + m] += acc[jt][t];
        }
    }
}

// ---------- fused relu + root2, 4 nodes/block: acc1->h; acc2 = h@Wroot2+b2 ----------
__global__ __launch_bounds__(256) void k_hrow(
    float* __restrict__ acc1, float* __restrict__ acc2,
    const float* __restrict__ Wroot2, const float* __restrict__ b2, int N)
{
    __shared__ __align__(16) float hS[4][64];
    int j = threadIdx.x & 63;
    int wv = threadIdx.x >> 6;
    int i = blockIdx.x*4 + wv;
    if (i >= N) return;
    size_t o64 = (size_t)i*64 + j;
    float h = fmaxf(acc1[o64], 0.f);
    acc1[o64] = h;
    hS[wv][j] = h;                                    // same-wave LDS
    float acc = b2[j];
    const float4* h4 = (const float4*)&hS[wv][0];
    #pragma unroll
    for (int c = 0; c < 16; ++c) {
        float4 f = h4[c];
        acc = fmaf(f.x, Wroot2[(4*c+0)*64+j], acc);
        acc = fmaf(f.y, Wroot2[(4*c+1)*64+j], acc);
        acc = fmaf(f.z, Wroot2[(4*c+2)*64+j], acc);
        acc = fmaf(f.w, Wroot2[(4*c+3)*64+j], acc);
    }
    acc2[o64] = acc;
}

// ---------- layer-2: run-wise max per (node,rel), rels [g0,g1), scalarized ----------
__global__ __launch_bounds__(256) void k_agg2(
    const int2* __restrict__ srec, const int* __restrict__ off8,
    const unsigned short* __restrict__ Ubf, size_t plane,
    float* __restrict__ acc2, int N, int g0, int g1)
{
    int lane = threadIdx.x & 63;
    int wv = threadIdx.x >> 6;
    int stride = gridDim.x*4;
    const float NEG = -__builtin_inff();
    for (int node = blockIdx.x*4 + wv; node < N; node += stride) {
        float add = 0.f;
        bool any = false;
        for (int r = g0; r < g1; ++r) {
            int s = rfl(off8[node*8 + r]);
            int e = rfl(off8[node*8 + r + 1]);
            if (s == e) continue;
            any = true;
            const unsigned short* Up = Ubf + (size_t)(r - g0)*plane;
            float mx = NEG;
            int i = s;
            for (; i + 8 <= e; i += 8) {
                int s0 = rfl(srec[i+0].x) & 0xFFFFFF, s1 = rfl(srec[i+1].x) & 0xFFFFFF;
                int s2 = rfl(srec[i+2].x) & 0xFFFFFF, s3 = rfl(srec[i+3].x) & 0xFFFFFF;
                int s4 = rfl(srec[i+4].x) & 0xFFFFFF, s5 = rfl(srec[i+5].x) & 0xFFFFFF;
                int s6 = rfl(srec[i+6].x) & 0xFFFFFF, s7 = rfl(srec[i+7].x) & 0xFFFFFF;
                float v0 = bf2f(Up[(size_t)s0*64 + lane]), v1 = bf2f(Up[(size_t)s1*64 + lane]);
                float v2 = bf2f(Up[(size_t)s2*64 + lane]), v3 = bf2f(Up[(size_t)s3*64 + lane]);
                float v4 = bf2f(Up[(size_t)s4*64 + lane]), v5 = bf2f(Up[(size_t)s5*64 + lane]);
                float v6 = bf2f(Up[(size_t)s6*64 + lane]), v7 = bf2f(Up[(size_t)s7*64 + lane]);
                float m01 = fmaxf(v0, v1), m23 = fmaxf(v2, v3);
                float m45 = fmaxf(v4, v5), m67 = fmaxf(v6, v7);
                mx = fmaxf(mx, fmaxf(fmaxf(m01, m23), fmaxf(m45, m67)));
            }
            for (; i < e; ++i) {
                int sx = rfl(srec[i].x) & 0xFFFFFF;
                mx = fmaxf(mx, bf2f(Up[(size_t)sx*64 + lane]));
            }
            add += mx;
        }
        if (any) acc2[(size_t)node*64 + lane] += add;
    }
}

// ---------- head, 4 nodes/block ----------
__global__ __launch_bounds__(256) void k_final(
    const float* __restrict__ acc2, const float* __restrict__ omega,
    const float* __restrict__ Wo, const float* __restrict__ bo,
    const float* __restrict__ Wagg, const float* __restrict__ bagg,
    const float* __restrict__ Wc, const float* __restrict__ bc,
    float* __restrict__ out, int N)
{
    __shared__ __align__(16) float cS[4][128];
    int j = threadIdx.x & 63;
    int wv = threadIdx.x >> 6;
    int i = blockIdx.x*4 + wv;
    if (i >= N) return;
    float om0 = omega[2*i], om1 = omega[2*i+1];
    float oj = fmaxf(fmaf(om1, Wo[64+j], fmaf(om0, Wo[j], bo[j])), 0.f);
    float h2 = fmaxf(acc2[(size_t)i*64 + j], 0.f);
    cS[wv][j] = h2;                                   // same-wave LDS
    cS[wv][64 + j] = oj;
    float t = bagg[j];
    const float4* c4 = (const float4*)&cS[wv][0];
    #pragma unroll
    for (int c = 0; c < 32; ++c) {
        float4 f = c4[c];
        t = fmaf(f.x, Wagg[(4*c+0)*64+j], t);
        t = fmaf(f.y, Wagg[(4*c+1)*64+j], t);
        t = fmaf(f.z, Wagg[(4*c+2)*64+j], t);
        t = fmaf(f.w, Wagg[(4*c+3)*64+j], t);
    }
    t = fmaxf(t, 0.f);
    float part = t * Wc[j];
    #pragma unroll
    for (int off = 32; off; off >>= 1) part += __shfl_xor(part, off);
    if (j == 0) out[i] = tanhf(part + bc[0]) * 5.0f;
}

extern "C" void kernel_launch(void* const* d_in, const int* in_sizes, int n_in,
                              void* d_out, int out_size, void* d_ws, size_t ws_size,
                              hipStream_t stream)
{
    const float* x      = (const float*)d_in[0];
    const int*   ei     = (const int*)d_in[1];
    const float* ea     = (const float*)d_in[2];
    const int*   et     = (const int*)d_in[3];
    const float* omega  = (const float*)d_in[4];
    const float* Wn     = (const float*)d_in[5];
    const float* bn     = (const float*)d_in[6];
    const float* We     = (const float*)d_in[7];
    const float* be     = (const float*)d_in[8];
    const float* Wo     = (const float*)d_in[9];
    const float* bo     = (const float*)d_in[10];
    const float* W1     = (const float*)d_in[11];
    const float* Wroot1 = (const float*)d_in[12];
    const float* b1     = (const float*)d_in[13];
    const float* W2     = (const float*)d_in[14];
    const float* Wroot2 = (const float*)d_in[15];
    const float* b2     = (const float*)d_in[16];
    const float* Wagg   = (const float*)d_in[17];
    const float* bagg   = (const float*)d_in[18];
    const float* Wc     = (const float*)d_in[19];
    const float* bc     = (const float*)d_in[20];
    int N = in_sizes[0] / 3;
    int E = in_sizes[3];
    float* out = (float*)d_out;

    int K8 = N*8;
    int nb = (K8 + SCHUNK - 1)/SCHUNK;

    // ---- workspace layout: every carve 256B-aligned ----
    #define ALIGN256(p) ((char*)(((size_t)(p) + 255) & ~(size_t)255))
    char* pp = (char*)d_ws;
    float* nbuf   = (float*)pp;  pp = ALIGN256(pp + (size_t)N*64*4);     // n; reused as acc2
    float* acc1   = (float*)pp;  pp = ALIGN256(pp + (size_t)N*64*4);     // acc1 -> h
    int2*  srec   = (int2*)pp;   pp = ALIGN256(pp + (size_t)E*8);        // (dst,rel)-sorted edges
    int*   deg8   = (int*)pp;    pp = ALIGN256(pp + (size_t)K8*4);
    int*   off8   = (int*)pp;    pp = ALIGN256(pp + (size_t)(K8+1)*4);
    int*   cursor = (int*)pp;    pp = ALIGN256(pp + (size_t)K8*4);
    int*   bsum   = (int*)pp;    pp = ALIGN256(pp + (size_t)nb*4);
    unsigned short* wpk = (unsigned short*)pp;
    pp = ALIGN256(pp + (size_t)40*4*64*16*2);                            // 320 KB
    unsigned short* Sepool = (unsigned short*)pp;
    pp = ALIGN256(pp + (size_t)N*256*2);                                 // [N][8][32] bf16, 51 MB
    size_t off = (size_t)(pp - (char*)d_ws);
    size_t planeElems = (size_t)N*64;
    size_t avail = (ws_size > off) ? (ws_size - off) : 0;
    int G = (int)(avail / (planeElems*2));                               // bf16 planes
    if (G > 8) G = 8;
    if (G < 1) G = 1;
    unsigned short* Vbf = (unsigned short*)pp;
    float* acc2 = nbuf;

    int nblocks4 = (N + 3)/4;
    k_encoder<<<nblocks4, 256, 0, stream>>>(x, Wn, bn, Wroot1, b1, nbuf, acc1, N);
    hipMemsetAsync(deg8, 0, (size_t)K8*4, stream);
    k_histd<<<(E + 255)/256, 256, 0, stream>>>(ei, et, deg8, E);
    k_bsum<<<nb, 256, 0, stream>>>(deg8, bsum, K8);
    k_bscan<<<1, 256, 0, stream>>>(bsum, nb);
    k_bapply<<<nb, 256, 0, stream>>>(deg8, bsum, off8, cursor, K8);
    k_scatd<<<(E + 255)/256, 256, 0, stream>>>(ei, ea, et, cursor, srec, E);
    k_wpack<<<160, 64, 0, stream>>>(W1, W2, wpk);

    int gblocks = (N + 63)/64;
    int aggBlocks = 4096;
    // ---- layer 1 ----
    int Gc1 = (G < 8) ? G : 8;
    k_vgemmB<<<gblocks, 256, 0, stream>>>(nbuf, wpk, 0, 0, Gc1, Vbf, planeElems, N);
    k_agg1e<<<aggBlocks, 256, 0, stream>>>(srec, off8, Vbf, planeElems, We, be,
                                           acc1, Sepool, N, Gc1);
    for (int g0 = Gc1; g0 < 8; g0 += G) {
        int Gc = (8 - g0 < G) ? (8 - g0) : G;
        k_vgemmB<<<gblocks, 256, 0, stream>>>(nbuf, wpk, 0, g0, Gc, Vbf, planeElems, N);
        k_agg1v<<<aggBlocks, 256, 0, stream>>>(srec, off8, Vbf, planeElems,
                                               acc1, N, g0, g0 + Gc);
    }
    k_segemm<<<gblocks, 256, 0, stream>>>(Sepool, wpk, acc1, N);
    k_hrow<<<nblocks4, 256, 0, stream>>>(acc1, acc2, Wroot2, b2, N);
    // ---- layer 2 ----
    for (int g0 = 0; g0 < 8; g0 += G) {
        int Gc = (8 - g0 < G) ? (8 - g0) : G;
        k_vgemmB<<<gblocks, 256, 0, stream>>>(acc1, wpk, 16, g0, Gc, Vbf, planeElems, N);
        k_agg2<<<aggBlocks, 256, 0, stream>>>(srec, off8, Vbf, planeElems,
                                              acc2, N, g0, g0 + Gc);
    }
    k_final<<<nblocks4, 256, 0, stream>>>(acc2, omega, Wo, bo, Wagg, bagg, Wc, bc, out, N);
}